// Round 4
// baseline (616.835 us; speedup 1.0000x reference)
//
#include <hip/hip_runtime.h>
#include <hip/hip_bf16.h>

typedef unsigned short u16;
typedef u16 u16x4 __attribute__((ext_vector_type(4)));
typedef __bf16 bf16x8 __attribute__((ext_vector_type(8)));
typedef float f32x4 __attribute__((ext_vector_type(4)));
typedef float f32x16 __attribute__((ext_vector_type(16)));

#define IN_DIM 4096
#define OUT_DIM 4096
#define M_TOT 8192   // 4 * 2048

__device__ __constant__ float NF4_LUT[16] = {
    -1.0f, -0.6961928009986877f, -0.5250730514526367f, -0.39491748809814453f,
    -0.28444138169288635f, -0.18477343022823334f, -0.09105003625154495f, 0.0f,
    0.07958029955625534f, 0.16093020141124725f, 0.24611230194568634f,
    0.33791524171829224f, 0.44070982933044434f, 0.5626170039176941f,
    0.7229568362236023f, 1.0f};

__device__ __forceinline__ u16 f2bf(float f) {  // round-to-nearest-even
  unsigned i = __float_as_uint(f);
  i += 0x7fffu + ((i >> 16) & 1u);
  return (u16)(i >> 16);
}

// ---------------------------------------------------------------------------
// Kernel 0: cast x fp32 -> bf16 into workspace.
// ---------------------------------------------------------------------------
__global__ __launch_bounds__(256) void convert_x(
    const float4* __restrict__ xin, u16x4* __restrict__ xout, int n4)
{
  int i = blockIdx.x * 256 + threadIdx.x;
  const int stride = gridDim.x * 256;
  for (; i < n4; i += stride) {
    const float4 v = xin[i];
    u16x4 o;
    o.x = f2bf(v.x); o.y = f2bf(v.y); o.z = f2bf(v.z); o.w = f2bf(v.w);
    xout[i] = o;
  }
}

// ---------------------------------------------------------------------------
// Kernel 1: dequantize NF4 -> fp32, fold LoRA (W_eff = W + 2*B*A), store bf16.
// 4 output rows per block: lora_a float4 loaded ONCE per block per position
// and reused for 4 rows in registers (L2 re-read traffic 1GB -> 256MB,
// arithmetic intensity x4).
// ---------------------------------------------------------------------------
__global__ __launch_bounds__(256) void dequant_fold(
    const int* __restrict__ nf4_idx, const int* __restrict__ q_scalers,
    const float* __restrict__ q_factor, const float* __restrict__ scaler_mean,
    const float* __restrict__ lora_a, const float* __restrict__ lora_b,
    u16* __restrict__ w_eff)
{
  __shared__ float s_lut[16];
  __shared__ float s_b[4][16];
  __shared__ float s_scl[4][64];
  const int t = threadIdx.x;
  const int o0 = blockIdx.x * 4;
  if (t < 16) s_lut[t] = NF4_LUT[t];
  if (t < 64) {
    const int row = t >> 4, r = t & 15;
    s_b[row][r] = 2.0f * lora_b[(o0 + row) * 16 + r];  // ALPHA/RANK = 2 folded
  }
  {
    const int row = t >> 6, blk = t & 63;
    const int b = (o0 + row) * 64 + blk;
    s_scl[row][blk] = (float)q_scalers[b] / q_factor[b >> 8] + scaler_mean[0];
  }
  __syncthreads();

#pragma unroll
  for (int it = 0; it < 4; ++it) {
    const int d0 = it * 1024 + t * 4;
    float4 lacc[4];
#pragma unroll
    for (int row = 0; row < 4; ++row) {
      lacc[row].x = 0.f; lacc[row].y = 0.f; lacc[row].z = 0.f; lacc[row].w = 0.f;
    }
#pragma unroll
    for (int r = 0; r < 16; ++r) {
      const float4 av = *(const float4*)(lora_a + (size_t)r * IN_DIM + d0);
#pragma unroll
      for (int row = 0; row < 4; ++row) {
        const float br = s_b[row][r];
        lacc[row].x += br * av.x;
        lacc[row].y += br * av.y;
        lacc[row].z += br * av.z;
        lacc[row].w += br * av.w;
      }
    }
#pragma unroll
    for (int row = 0; row < 4; ++row) {
      const int o = o0 + row;
      const int4 iv = *(const int4*)(nf4_idx + (size_t)o * IN_DIM + d0);
      const float sc = s_scl[row][d0 >> 6];
      u16x4 ov;
      ov.x = f2bf(s_lut[iv.x] * sc + lacc[row].x);
      ov.y = f2bf(s_lut[iv.y] * sc + lacc[row].y);
      ov.z = f2bf(s_lut[iv.z] * sc + lacc[row].z);
      ov.w = f2bf(s_lut[iv.w] * sc + lacc[row].w);
      *(u16x4*)(w_eff + (size_t)o * IN_DIM + d0) = ov;
    }
  }
}

// ---------------------------------------------------------------------------
// Kernel 2: bf16 GEMM 256x256, BK=64, 8 waves (2Mx4N), 32x32x16 MFMA.
// Per wave: 128x64 output = 4x2 tiles of 32x32 (acc = 8 x f32x16 = 128 VGPR),
// 32 MFMA / K-tile.  Matrix-pipe floor 17% lower than 16x16x32 and half the
// MFMA instruction count (deeper per-instr latency hiding).  3 barriers/tile
// (was 8).  Staging / LDS chunk-XOR swizzle identical to verified R1 kernel.
//   P1: 24 ds_reads (kk01 first); bar; setprio MFMA16(kk01); lgkm0; bar(WAR)
//   P2: setprio MFMA16(kk23); STG x4 (tile t+2 -> buf c); vmcnt(8); bar
// vmcnt induction: at vmcnt point, outstanding = t+1's 8 + t+2's 8; wait to 8
// drains t+1 exactly (needed by next tile), keeps t+2 in flight.
// ---------------------------------------------------------------------------
#define BM 256
#define BN 256
#define BK 64
#define NT (IN_DIM / BK)   // 64 K-tiles

__device__ __forceinline__ void async16(const u16* g, const u16* l) {
  __builtin_amdgcn_global_load_lds(
      (const __attribute__((address_space(1))) void*)g,
      (__attribute__((address_space(3))) void*)l,
      16, 0, 0);
}

// Stage one 64-row group (j) of A and B for buffer c at k-offset kt.
// Wave-uniform LDS base; HW adds lane*16B.  Global source row = base + j*64 +
// (tid>>3), chunk = (tid&7) ^ ((tid>>3)&7) — inverse swizzle (rule #21).
#define STG(c, kt, j) do {                                                     \
    async16(gA + (size_t)(j) * 64 * IN_DIM + (kt),                             \
            &sA[(c) * BM * BK + ((j) * 512 + wid * 64) * 8]);                  \
    async16(gB + (size_t)(j) * 64 * IN_DIM + (kt),                             \
            &sB[(c) * BN * BK + ((j) * 512 + wid * 64) * 8]);                  \
  } while (0)

// One half-K cluster: 4 mtiles x 2 ntiles x 2 ksteps = 16 MFMA (32x32x16).
#define MFMA16x32(AF, BF) do {                                                 \
    _Pragma("unroll") for (int mt = 0; mt < 4; ++mt)                           \
    _Pragma("unroll") for (int nt = 0; nt < 2; ++nt)                           \
    _Pragma("unroll") for (int kk = 0; kk < 2; ++kk)                           \
      acc[mt][nt] = __builtin_amdgcn_mfma_f32_32x32x16_bf16(                   \
          AF[mt][kk], BF[nt][kk], acc[mt][nt], 0, 0, 0);                       \
  } while (0)

#define KTILE32(c, ktn, DOSTAGE, DOVM, VMSTR) do {                             \
  /* P1: all 24 frag reads of buf c (kk01 group first) */                      \
  _Pragma("unroll") for (int mt = 0; mt < 4; ++mt)                             \
  _Pragma("unroll") for (int kk = 0; kk < 2; ++kk)                             \
    a0[mt][kk] = *(const bf16x8*)&sA[(c) * BM * BK + aBase + mt * 2048 + eK[kk]];\
  _Pragma("unroll") for (int nt = 0; nt < 2; ++nt)                             \
  _Pragma("unroll") for (int kk = 0; kk < 2; ++kk)                             \
    b0[nt][kk] = *(const bf16x8*)&sB[(c) * BN * BK + bBase + nt * 2048 + eK[kk]];\
  _Pragma("unroll") for (int mt = 0; mt < 4; ++mt)                             \
  _Pragma("unroll") for (int kk = 0; kk < 2; ++kk)                             \
    a1[mt][kk] = *(const bf16x8*)&sA[(c) * BM * BK + aBase + mt * 2048 + eK[2 + kk]];\
  _Pragma("unroll") for (int nt = 0; nt < 2; ++nt)                             \
  _Pragma("unroll") for (int kk = 0; kk < 2; ++kk)                             \
    b1[nt][kk] = *(const bf16x8*)&sB[(c) * BN * BK + bBase + nt * 2048 + eK[2 + kk]];\
  __builtin_amdgcn_s_barrier();                                                \
  __builtin_amdgcn_s_setprio(1);                                               \
  MFMA16x32(a0, b0);           /* kk23 reads drain underneath */               \
  __builtin_amdgcn_s_setprio(0);                                               \
  asm volatile("s_waitcnt lgkmcnt(0)" ::: "memory");                           \
  __builtin_amdgcn_s_barrier();  /* all waves done reading buf c */            \
  /* P2: second cluster (register-only), then stage tile t+2 into buf c */     \
  __builtin_amdgcn_s_setprio(1);                                               \
  MFMA16x32(a1, b1);                                                           \
  __builtin_amdgcn_s_setprio(0);                                               \
  if (DOSTAGE) { STG(c, ktn, 0); STG(c, ktn, 1); STG(c, ktn, 2); STG(c, ktn, 3); }\
  if (DOVM) { asm volatile("s_waitcnt " VMSTR ::: "memory"); }                 \
  __builtin_amdgcn_s_barrier();  /* tile t+1 certified landed for all waves */ \
} while (0)

__global__ __launch_bounds__(512, 2) void gemm256(
    const u16* __restrict__ X, const u16* __restrict__ W,
    float* __restrict__ Out)
{
  __shared__ __align__(16) u16 sA[2 * BM * BK];   // 64 KiB
  __shared__ __align__(16) u16 sB[2 * BN * BK];   // 64 KiB

  const int tid = threadIdx.x;
  const int lane = tid & 63;
  const int wid = tid >> 6;          // 0..7
  const int wm = wid >> 2;           // 0..1  (M half)
  const int wn = wid & 3;            // 0..3  (N quarter)

  // XCD-bijective block swizzle: 512 wgs, 512 % 8 == 0 -> simple form valid.
  const int bid = blockIdx.x;
  const int swzb = (bid & 7) * 64 + (bid >> 3);
  const int tileM = swzb >> 4;       // 0..31
  const int tileN = swzb & 15;       // 0..15
  const int rowBase = tileM * BM;
  const int colBase = tileN * BN;

  // Staging source: row-group row (tid>>3), inverse-swizzled chunk.
  const int cr = tid >> 3;           // 0..63
  const int cq = tid & 7;            // 0..7
  const int qsw = cq ^ (cr & 7);
  const u16* gA = X + (size_t)(rowBase + cr) * IN_DIM + qsw * 8;
  const u16* gB = W + (size_t)(colBase + cr) * IN_DIM + qsw * 8;

  // 32x32x16 fragment addressing.  A: row = lane&31, k = (lane>>5)*8 + j.
  // LDS row-major [row][8 chunks of 8 elems], physical chunk = q ^ (row&7);
  // row offsets are multiples of 32 so (row&7) == (lane&7).
  const int l31 = lane & 31;
  const int khalf = lane >> 5;       // 0..1
  const int l7 = lane & 7;
  int eK[4];
#pragma unroll
  for (int kk = 0; kk < 4; ++kk)
    eK[kk] = ((kk * 2 + khalf) ^ l7) * 8;   // elem offset within row
  const int aBase = (wm * 128 + l31) * 64;
  const int bBase = (wn * 64 + l31) * 64;

  f32x16 acc[4][2] = {};
  bf16x8 a0[4][2], a1[4][2], b0[2][2], b1[2][2];

  // Prologue: stage tiles 0 (buf0) and 1 (buf1); land tile 0, keep tile 1
  // in flight (vmcnt(8)).
  STG(0, 0, 0); STG(0, 0, 1); STG(0, 0, 2); STG(0, 0, 3);
  STG(1, BK, 0); STG(1, BK, 1); STG(1, BK, 2); STG(1, BK, 3);
  asm volatile("s_waitcnt vmcnt(8)" ::: "memory");
  __builtin_amdgcn_s_barrier();

  // Main loop: tiles 0..NT-3 stage tile t+2 into their own buffer.
  int kt2 = 2 * BK;
  for (int t = 0; t < NT - 2; t += 2) {
    KTILE32(0, kt2, true, true, "vmcnt(8)");
    KTILE32(1, kt2 + BK, true, true, "vmcnt(8)");
    kt2 += 2 * BK;
  }
  // Epilogue: tile NT-2 drains tile NT-1's loads; tile NT-1 computes only.
  KTILE32(0, 0, false, true, "vmcnt(0)");
  KTILE32(1, 0, false, false, "vmcnt(0)");

  // Epilogue: C/D layout (32x32): col = lane&31, row = (r&3)+8*(r>>2)+4*khalf.
#pragma unroll
  for (int mt = 0; mt < 4; ++mt) {
#pragma unroll
    for (int nt = 0; nt < 2; ++nt) {
#pragma unroll
      for (int r = 0; r < 16; ++r) {
        const int rloc = (r & 3) + 8 * (r >> 2) + 4 * khalf;
        const size_t row = (size_t)(rowBase + wm * 128 + mt * 32 + rloc);
        Out[row * OUT_DIM + colBase + wn * 64 + nt * 32 + l31] = acc[mt][nt][r];
      }
    }
  }
}

extern "C" void kernel_launch(void* const* d_in, const int* in_sizes, int n_in,
                              void* d_out, int out_size, void* d_ws, size_t ws_size,
                              hipStream_t stream) {
  const float* x         = (const float*)d_in[0];
  const int* nf4_idx     = (const int*)d_in[1];
  const int* q_scalers   = (const int*)d_in[2];
  const float* q_factor  = (const float*)d_in[3];
  const float* scaler_mean = (const float*)d_in[4];
  const float* lora_a    = (const float*)d_in[5];
  const float* lora_b    = (const float*)d_in[6];
  float* out = (float*)d_out;

  // ws layout: [0, 64MB) x as bf16; [64MB, 96MB) W_eff as bf16.
  const size_t xbf_bytes = (size_t)M_TOT * IN_DIM * sizeof(u16);
  const size_t wef_bytes = (size_t)OUT_DIM * IN_DIM * sizeof(u16);
  if (ws_size < xbf_bytes + wef_bytes) return;  // need 96 MB
  u16* xbf   = (u16*)d_ws;
  u16* w_eff = (u16*)((char*)d_ws + xbf_bytes);

  hipLaunchKernelGGL(convert_x, dim3(8192), dim3(256), 0, stream,
                     (const float4*)x, (u16x4*)xbf, M_TOT * IN_DIM / 4);
  hipLaunchKernelGGL(dequant_fold, dim3(OUT_DIM / 4), dim3(256), 0, stream,
                     nf4_idx, q_scalers, q_factor, scaler_mean, lora_a, lora_b,
                     w_eff);
  hipLaunchKernelGGL(gemm256, dim3((M_TOT / BM) * (OUT_DIM / BN)), dim3(512),
                     0, stream, xbf, w_eff, out);
}

// Round 7
// 518.867 us; speedup vs baseline: 1.1888x; 1.1888x over previous
//
#include <hip/hip_runtime.h>
#include <hip/hip_bf16.h>

typedef unsigned short u16;
typedef u16 u16x4 __attribute__((ext_vector_type(4)));
typedef __bf16 bf16x8 __attribute__((ext_vector_type(8)));
typedef float f32x4 __attribute__((ext_vector_type(4)));

#define IN_DIM 4096
#define OUT_DIM 4096
#define M_TOT 8192   // 4 * 2048

__device__ __constant__ float NF4_LUT[16] = {
    -1.0f, -0.6961928009986877f, -0.5250730514526367f, -0.39491748809814453f,
    -0.28444138169288635f, -0.18477343022823334f, -0.09105003625154495f, 0.0f,
    0.07958029955625534f, 0.16093020141124725f, 0.24611230194568634f,
    0.33791524171829224f, 0.44070982933044434f, 0.5626170039176941f,
    0.7229568362236023f, 1.0f};

__device__ __forceinline__ u16 f2bf(float f) {  // round-to-nearest-even
  unsigned i = __float_as_uint(f);
  i += 0x7fffu + ((i >> 16) & 1u);
  return (u16)(i >> 16);
}

// ---------------------------------------------------------------------------
// Kernel 0: fused prep.  Blocks [0,1024): dequantize NF4 + fold LoRA
// (W_eff = W + 2*B*A) -> bf16, 4 rows/block (verified in round 4).
// Blocks [1024, 9216): cast x fp32 -> bf16 (verified rounds 1-4).
// Wave-uniform branch on blockIdx; one launch instead of two.
// ---------------------------------------------------------------------------
__global__ __launch_bounds__(256) void prep_fused(
    const float4* __restrict__ xin, u16x4* __restrict__ xout, int n4,
    const int* __restrict__ nf4_idx, const int* __restrict__ q_scalers,
    const float* __restrict__ q_factor, const float* __restrict__ scaler_mean,
    const float* __restrict__ lora_a, const float* __restrict__ lora_b,
    u16* __restrict__ w_eff)
{
  const int t = threadIdx.x;
  if (blockIdx.x >= 1024) {
    // ---- convert_x part ----
    int i = (blockIdx.x - 1024) * 256 + t;
    const int stride = 8192 * 256;
    for (; i < n4; i += stride) {
      const float4 v = xin[i];
      u16x4 o;
      o.x = f2bf(v.x); o.y = f2bf(v.y); o.z = f2bf(v.z); o.w = f2bf(v.w);
      xout[i] = o;
    }
    return;
  }
  // ---- dequant_fold part (4 rows per block) ----
  __shared__ float s_lut[16];
  __shared__ float s_b[4][16];
  __shared__ float s_scl[4][64];
  const int o0 = blockIdx.x * 4;
  if (t < 16) s_lut[t] = NF4_LUT[t];
  if (t < 64) {
    const int row = t >> 4, r = t & 15;
    s_b[row][r] = 2.0f * lora_b[(o0 + row) * 16 + r];  // ALPHA/RANK = 2 folded
  }
  {
    const int row = t >> 6, blk = t & 63;
    const int b = (o0 + row) * 64 + blk;
    s_scl[row][blk] = (float)q_scalers[b] / q_factor[b >> 8] + scaler_mean[0];
  }
  __syncthreads();

#pragma unroll
  for (int it = 0; it < 4; ++it) {
    const int d0 = it * 1024 + t * 4;
    float4 lacc[4];
#pragma unroll
    for (int row = 0; row < 4; ++row) {
      lacc[row].x = 0.f; lacc[row].y = 0.f; lacc[row].z = 0.f; lacc[row].w = 0.f;
    }
#pragma unroll
    for (int r = 0; r < 16; ++r) {
      const float4 av = *(const float4*)(lora_a + (size_t)r * IN_DIM + d0);
#pragma unroll
      for (int row = 0; row < 4; ++row) {
        const float br = s_b[row][r];
        lacc[row].x += br * av.x;
        lacc[row].y += br * av.y;
        lacc[row].z += br * av.z;
        lacc[row].w += br * av.w;
      }
    }
#pragma unroll
    for (int row = 0; row < 4; ++row) {
      const int o = o0 + row;
      const int4 iv = *(const int4*)(nf4_idx + (size_t)o * IN_DIM + d0);
      const float sc = s_scl[row][d0 >> 6];
      u16x4 ov;
      ov.x = f2bf(s_lut[iv.x] * sc + lacc[row].x);
      ov.y = f2bf(s_lut[iv.y] * sc + lacc[row].y);
      ov.z = f2bf(s_lut[iv.z] * sc + lacc[row].z);
      ov.w = f2bf(s_lut[iv.w] * sc + lacc[row].w);
      *(u16x4*)(w_eff + (size_t)o * IN_DIM + d0) = ov;
    }
  }
}

// ---------------------------------------------------------------------------
// Kernel 2: bf16 GEMM, 256x256 8-phase structure — ROUND-1 VERIFIED KERNEL,
// byte-identical (295 us, 932 TF, MfmaUtil 40%, 0 bank conflicts).  The
// JIT-quadrant rewrite (rounds 4-5) raced on HW (absmax 10.4) — reverted;
// schedule lane closed per round-4 pre-commitment.
// ---------------------------------------------------------------------------
#define BM 256
#define BN 256
#define BK 64
#define NT (IN_DIM / BK)   // 64 K-tiles

__device__ __forceinline__ void async16(const u16* g, const u16* l) {
  __builtin_amdgcn_global_load_lds(
      (const __attribute__((address_space(1))) void*)g,
      (__attribute__((address_space(3))) void*)l,
      16, 0, 0);
}

#define STG(c, kt, j) do {                                                     \
    async16(gA + (size_t)(j) * 64 * IN_DIM + (kt),                             \
            &sA[(c) * BM * BK + ((j) * 512 + wid * 64) * 8]);                  \
    async16(gB + (size_t)(j) * 64 * IN_DIM + (kt),                             \
            &sB[(c) * BN * BK + ((j) * 512 + wid * 64) * 8]);                  \
  } while (0)

#define MFMA_Q(AF, BF, MI0) do {                                               \
    _Pragma("unroll") for (int mi = (MI0); mi < (MI0) + 4; ++mi)               \
    _Pragma("unroll") for (int ni = 0; ni < 4; ++ni)                           \
      acc[mi][ni] = __builtin_amdgcn_mfma_f32_16x16x32_bf16(                   \
          AF[mi], BF[ni], acc[mi][ni], 0, 0, 0);                               \
  } while (0)

#define KTILE(c, ktn, DOSTAGE, ENDVM_STR, DOENDBAR) do {                       \
  /* phase 1: read A k0 (8), B k0 (4); MFMA k0 x mi0-3 */                      \
  _Pragma("unroll") for (int mi = 0; mi < 8; ++mi)                             \
    a0[mi] = *(const bf16x8*)&sA[(c) * BM * BK + aBase + mi * 1024 + e0];      \
  _Pragma("unroll") for (int ni = 0; ni < 4; ++ni)                             \
    b0[ni] = *(const bf16x8*)&sB[(c) * BN * BK + bBase + ni * 1024 + e0];      \
  __builtin_amdgcn_s_barrier();                                                \
  asm volatile("s_waitcnt lgkmcnt(0)" ::: "memory");                           \
  __builtin_amdgcn_s_setprio(1);                                               \
  MFMA_Q(a0, b0, 0);                                                           \
  __builtin_amdgcn_s_setprio(0);                                               \
  __builtin_amdgcn_s_barrier();                                                \
  /* phase 2: read A k1 (8), B k1 (4); MFMA k0 x mi4-7 */                      \
  _Pragma("unroll") for (int mi = 0; mi < 8; ++mi)                             \
    a1[mi] = *(const bf16x8*)&sA[(c) * BM * BK + aBase + mi * 1024 + e1];      \
  _Pragma("unroll") for (int ni = 0; ni < 4; ++ni)                             \
    b1[ni] = *(const bf16x8*)&sB[(c) * BN * BK + bBase + ni * 1024 + e1];      \
  __builtin_amdgcn_s_barrier();                                                \
  asm volatile("s_waitcnt lgkmcnt(0)" ::: "memory");                           \
  __builtin_amdgcn_s_setprio(1);                                               \
  MFMA_Q(a0, b0, 4);                                                           \
  __builtin_amdgcn_s_setprio(0);                                               \
  __builtin_amdgcn_s_barrier();                                                \
  /* phase 3: stage half of next-next tile; MFMA k1 x mi0-3 */                 \
  if (DOSTAGE) { STG(c, ktn, 0); STG(c, ktn, 1); }                             \
  __builtin_amdgcn_s_barrier();                                                \
  __builtin_amdgcn_s_setprio(1);                                               \
  MFMA_Q(a1, b1, 0);                                                           \
  __builtin_amdgcn_s_setprio(0);                                               \
  __builtin_amdgcn_s_barrier();                                                \
  /* phase 4: stage other half; MFMA k1 x mi4-7; counted vmcnt */              \
  if (DOSTAGE) { STG(c, ktn, 2); STG(c, ktn, 3); }                             \
  __builtin_amdgcn_s_barrier();                                                \
  __builtin_amdgcn_s_setprio(1);                                               \
  MFMA_Q(a1, b1, 4);                                                           \
  __builtin_amdgcn_s_setprio(0);                                               \
  asm volatile("s_waitcnt " ENDVM_STR ::: "memory");                           \
  if (DOENDBAR) __builtin_amdgcn_s_barrier();                                  \
} while (0)

__global__ __launch_bounds__(512, 2) void gemm256(
    const u16* __restrict__ X, const u16* __restrict__ W,
    float* __restrict__ Out)
{
  __shared__ __align__(16) u16 sA[2 * BM * BK];   // 64 KiB
  __shared__ __align__(16) u16 sB[2 * BN * BK];   // 64 KiB

  const int tid = threadIdx.x;
  const int lane = tid & 63;
  const int wid = tid >> 6;          // 0..7
  const int wm = wid >> 2;           // 0..1  (M half)
  const int wn = wid & 3;            // 0..3  (N quarter)

  // XCD-bijective block swizzle: 512 wgs, 512 % 8 == 0 -> simple form valid.
  const int bid = blockIdx.x;
  const int swzb = (bid & 7) * 64 + (bid >> 3);
  const int tileM = swzb >> 4;       // 0..31
  const int tileN = swzb & 15;       // 0..15
  const int rowBase = tileM * BM;
  const int colBase = tileN * BN;

  // Staging source: row-group row (tid>>3), inverse-swizzled chunk.
  const int cr = tid >> 3;           // 0..63
  const int cq = tid & 7;            // 0..7
  const int qsw = cq ^ (cr & 7);
  const u16* gA = X + (size_t)(rowBase + cr) * IN_DIM + qsw * 8;
  const u16* gB = W + (size_t)(colBase + cr) * IN_DIM + qsw * 8;

  // ds_read fragment addressing (swizzled): physical chunk = q ^ (lane&7).
  const int l15 = lane & 15;
  const int qhi = lane >> 4;         // 0..3
  const int l7 = lane & 7;
  const int e0 = (qhi ^ l7) * 8;           // krep 0 chunk offset (elems)
  const int e1 = ((4 + qhi) ^ l7) * 8;     // krep 1
  const int aBase = (wm * 128 + l15) * 64;
  const int bBase = (wn * 64 + l15) * 64;

  f32x4 acc[4 + 4][4] = {};
  bf16x8 a0[8], a1[8], b0[4], b1[4];

  // Staging: 8 KB per tile = 512 16B-chunks; wave-uniform LDS dest.
  // Prologue: stage K-tiles 0 (buf0) and 1 (buf1); wait tile 0 only.
  STG(0, 0, 0); STG(0, 0, 1); STG(0, 0, 2); STG(0, 0, 3);
  STG(1, BK, 0); STG(1, BK, 1); STG(1, BK, 2); STG(1, BK, 3);
  asm volatile("s_waitcnt vmcnt(8)" ::: "memory");
  __builtin_amdgcn_s_barrier();

  // Main loop: 62 K-tiles, each staging K-tile t+2 and ending vmcnt(8).
  int kt2 = 2 * BK;
  for (int t = 0; t < NT - 2; t += 2) {
    KTILE(0, kt2, true, "vmcnt(8)", true);
    KTILE(1, kt2 + BK, true, "vmcnt(8)", true);
    kt2 += 2 * BK;
  }
  // Epilogue: last two K-tiles, no staging; drain before the final tile.
  KTILE(0, 0, false, "vmcnt(0)", true);
  KTILE(1, 0, false, "vmcnt(0)", false);

  // C/D layout: col = lane&15 (+ni*16), row = (lane>>4)*4 + i.  fp32 stores.
  const int or4 = qhi * 4;
#pragma unroll
  for (int mi = 0; mi < 8; ++mi) {
#pragma unroll
    for (int i = 0; i < 4; ++i) {
      const size_t r = (size_t)(rowBase + wm * 128 + mi * 16 + or4 + i);
      float* po = Out + r * OUT_DIM + colBase + wn * 64 + l15;
#pragma unroll
      for (int ni = 0; ni < 4; ++ni)
        po[ni * 16] = acc[mi][ni][i];
    }
  }
}

extern "C" void kernel_launch(void* const* d_in, const int* in_sizes, int n_in,
                              void* d_out, int out_size, void* d_ws, size_t ws_size,
                              hipStream_t stream) {
  const float* x         = (const float*)d_in[0];
  const int* nf4_idx     = (const int*)d_in[1];
  const int* q_scalers   = (const int*)d_in[2];
  const float* q_factor  = (const float*)d_in[3];
  const float* scaler_mean = (const float*)d_in[4];
  const float* lora_a    = (const float*)d_in[5];
  const float* lora_b    = (const float*)d_in[6];
  float* out = (float*)d_out;

  // ws layout: [0, 64MB) x as bf16; [64MB, 96MB) W_eff as bf16.
  const size_t xbf_bytes = (size_t)M_TOT * IN_DIM * sizeof(u16);
  const size_t wef_bytes = (size_t)OUT_DIM * IN_DIM * sizeof(u16);
  if (ws_size < xbf_bytes + wef_bytes) return;  // need 96 MB
  u16* xbf   = (u16*)d_ws;
  u16* w_eff = (u16*)((char*)d_ws + xbf_bytes);

  hipLaunchKernelGGL(prep_fused, dim3(1024 + 8192), dim3(256), 0, stream,
                     (const float4*)x, (u16x4*)xbf, M_TOT * IN_DIM / 4,
                     nf4_idx, q_scalers, q_factor, scaler_mean, lora_a, lora_b,
                     w_eff);
  hipLaunchKernelGGL(gemm256, dim3((M_TOT / BM) * (OUT_DIM / BN)), dim3(512),
                     0, stream, xbf, w_eff, out);
}